// Round 8
// baseline (370.939 us; speedup 1.0000x reference)
//
#include <hip/hip_runtime.h>
#include <hip/hip_bf16.h>

#define D 128
#define EPSV 1e-5f

static inline int cdiv(int a, int b) { return (a + b - 1) / b; }

// bf16 RNE pack
__device__ __forceinline__ unsigned short f2bf(float f) {
    unsigned int x = __float_as_uint(f);
    unsigned int r = x + 0x7fffu + ((x >> 16) & 1u);
    return (unsigned short)(r >> 16);
}

// ---------------- edge preprocessing (fully deterministic) ----------------

__global__ void hist_kernel(const int* __restrict__ col, int* __restrict__ cnt, int E_) {
    int e = blockIdx.x * blockDim.x + threadIdx.x;
    if (e >= E_) return;
    atomicAdd(&cnt[col[e]], 1);  // int atomics: result order-independent
}

// scan over cnt[N] (chunk = 1024): block sums, then final scan (tops fused)
__global__ void scan_chunk_sums(const int* __restrict__ cnt, int* __restrict__ bsum, int n) {
    __shared__ int sm[1024];
    int i = blockIdx.x * 1024 + threadIdx.x;
    sm[threadIdx.x] = (i < n) ? cnt[i] : 0;
    __syncthreads();
    for (int off = 512; off > 0; off >>= 1) {
        if (threadIdx.x < off) sm[threadIdx.x] += sm[threadIdx.x + off];
        __syncthreads();
    }
    if (threadIdx.x == 0) bsum[blockIdx.x] = sm[0];
}

__global__ void scan_final(const int* __restrict__ cnt, const int* __restrict__ bsum, int nbk,
                           int* __restrict__ offs, int* __restrict__ cursor, int n, int E_) {
    __shared__ int sm[1024];
    __shared__ int sbo;
    int tid = threadIdx.x;
    int bv = (tid < nbk && tid < blockIdx.x) ? bsum[tid] : 0;
    sm[tid] = bv;
    __syncthreads();
    for (int off = 512; off > 0; off >>= 1) {
        if (tid < off) sm[tid] += sm[tid + off];
        __syncthreads();
    }
    if (tid == 0) {
        sbo = sm[0];
        if (blockIdx.x == 0) offs[n] = E_;
    }
    __syncthreads();
    int i = blockIdx.x * 1024 + tid;
    int v = (i < n) ? cnt[i] : 0;
    sm[tid] = v;
    __syncthreads();
    for (int off = 1; off < 1024; off <<= 1) {
        int t = (tid >= off) ? sm[tid - off] : 0;
        __syncthreads();
        sm[tid] += t;
        __syncthreads();
    }
    if (i < n) {
        int excl = sm[tid] - v + sbo;
        offs[i] = excl;
        cursor[i] = excl;
    }
}

// scatter packed (edge_id<<32 | src_row) into CSR slots; row read is coalesced
// here so later phases never gather row[] randomly.
__global__ void scatter_pack(const int* __restrict__ row, const int* __restrict__ col,
                             int* __restrict__ cursor, long long* __restrict__ pk, int E_) {
    int e = blockIdx.x * blockDim.x + threadIdx.x;
    if (e >= E_) return;
    int c = col[e];
    int r = row[e];
    int p = atomicAdd(&cursor[c], 1);
    pk[p] = ((long long)e << 32) | (unsigned int)r;
}

// wave-level bitonic sort of each node's packed edges (key = edge id, payload
// = src row); gathers ea[e] once (needed for deg anyway), writes csr=(r, ea)
// coalesced, deterministic tree-sum for deg -> dis.
__global__ __launch_bounds__(256) void sort_deg_kernel(const long long* __restrict__ pk,
                                                       const int* __restrict__ offs,
                                                       const float* __restrict__ ea,
                                                       float* __restrict__ dis,
                                                       int2* __restrict__ csr, int n) {
    int node = blockIdx.x * 4 + (threadIdx.x >> 6);
    int lane = threadIdx.x & 63;
    if (node >= n) return;
    int p0 = offs[node], p1 = offs[node + 1];
    int deg = p1 - p0;
    if (deg <= 64) {
        long long v = (lane < deg) ? pk[p0 + lane] : 0x7fffffffffffffffLL;
        for (int k = 2; k <= 64; k <<= 1) {
            for (int j = k >> 1; j > 0; j >>= 1) {
                long long partner = __shfl_xor(v, j, 64);
                bool up = ((lane & k) == 0);
                bool keepMin = ((lane & j) == 0);
                long long mn = v < partner ? v : partner;
                long long mx = v < partner ? partner : v;
                v = (up == keepMin) ? mn : mx;
            }
        }
        int e = (int)(v >> 32);
        int r = (int)(v & 0xffffffffLL);
        float av = (lane < deg) ? ea[e] : 0.f;
        if (lane < deg) csr[p0 + lane] = make_int2(r, __float_as_int(av));
        float s = av;
        for (int off = 32; off > 0; off >>= 1) s += __shfl_xor(s, off, 64);
        if (lane == 0) dis[node] = s > 0.f ? rsqrtf(fmaxf(s, EPSV)) : 0.f;
    } else {
        // serial fallback (unreachable for this degree distribution)
        if (lane == 0) {
            // insertion sort of packed values in global
            for (int a = p0 + 1; a < p1; ++a) {
                long long key = pk[a];
                int b = a - 1;
                // note pk is const; fallback sorts via csr staging instead
                (void)key; (void)b;
            }
            // simple O(d^2) selection into csr (deterministic)
            float dg = 0.f;
            for (int p = p0; p < p1; ++p) {
                // find p-th smallest
                long long best = 0x7fffffffffffffffLL;
                for (int q2 = p0; q2 < p1; ++q2) {
                    long long cand = pk[q2];
                    int less = 0;
                    for (int q3 = p0; q3 < p1; ++q3)
                        if (pk[q3] < cand) ++less;
                    if (less == p - p0) { best = cand; break; }
                }
                int e = (int)(best >> 32);
                int r = (int)(best & 0xffffffffLL);
                float av = ea[e];
                csr[p] = make_int2(r, __float_as_int(av));
                dg += av;
            }
            dis[node] = dg > 0.f ? rsqrtf(fmaxf(dg, EPSV)) : 0.f;
        }
    }
}

// finalize weights: csr=(r, ea) -> (r, dis[r]*ea*dis[c]); wave per node so
// dis[c] is wave-uniform; only dis[r] is a random gather.
__global__ __launch_bounds__(256) void fill_w_kernel(const int* __restrict__ offs,
                                                     const float* __restrict__ dis,
                                                     int2* __restrict__ csr, int n) {
    int node = blockIdx.x * 4 + (threadIdx.x >> 6);
    int lane = threadIdx.x & 63;
    if (node >= n) return;
    int p0 = offs[node], p1 = offs[node + 1];
    float dc = dis[node];
    for (int p = p0 + lane; p < p1; p += 64) {
        int2 pr = csr[p];
        float w = dis[pr.x] * __int_as_float(pr.y) * dc;
        csr[p] = make_int2(pr.x, __float_as_int(w));
    }
}

// ---------------- batch norm (deterministic partials) ----------------
// 256 threads = 8 rows x 32 lanes (float4 each); idx prefetched one iteration
// ahead to break the idx->row dependent chain; partials TRANSPOSED.

template <bool GATHER>
__global__ __launch_bounds__(256) void bn_stats(const float* __restrict__ src,
                                                const int* __restrict__ idx,
                                                float* __restrict__ pS,
                                                float* __restrict__ pQ, int n, int NB) {
    int sub = threadIdx.x >> 5;
    int q = threadIdx.x & 31;
    float4 s = make_float4(0, 0, 0, 0), s2 = make_float4(0, 0, 0, 0);
    int stride = gridDim.x * 8;
    int i = blockIdx.x * 8 + sub;
    int r_next = (i < n) ? (GATHER ? idx[i] : i) : 0;
    for (; i < n; i += stride) {
        int r = r_next;
        int i2 = i + stride;
        if (i2 < n) r_next = GATHER ? idx[i2] : i2;
        float4 v = *(const float4*)&src[(long)r * D + q * 4];
        s.x += v.x; s.y += v.y; s.z += v.z; s.w += v.w;
        s2.x += v.x * v.x; s2.y += v.y * v.y; s2.z += v.z * v.z; s2.w += v.w * v.w;
    }
    __shared__ float4 redA[256], redB[256];
    redA[threadIdx.x] = s;
    redB[threadIdx.x] = s2;
    __syncthreads();
    for (int off = 128; off >= 32; off >>= 1) {
        if (threadIdx.x < off) {
            float4 a = redA[threadIdx.x + off], b = redB[threadIdx.x + off];
            redA[threadIdx.x].x += a.x; redA[threadIdx.x].y += a.y;
            redA[threadIdx.x].z += a.z; redA[threadIdx.x].w += a.w;
            redB[threadIdx.x].x += b.x; redB[threadIdx.x].y += b.y;
            redB[threadIdx.x].z += b.z; redB[threadIdx.x].w += b.w;
        }
        __syncthreads();
    }
    if (threadIdx.x < 32) {
        float4 a = redA[threadIdx.x], b = redB[threadIdx.x];
        int bofs = blockIdx.x;
        pS[(q * 4 + 0) * NB + bofs] = a.x;
        pS[(q * 4 + 1) * NB + bofs] = a.y;
        pS[(q * 4 + 2) * NB + bofs] = a.z;
        pS[(q * 4 + 3) * NB + bofs] = a.w;
        pQ[(q * 4 + 0) * NB + bofs] = b.x;
        pQ[(q * 4 + 1) * NB + bofs] = b.y;
        pQ[(q * 4 + 2) * NB + bofs] = b.z;
        pQ[(q * 4 + 3) * NB + bofs] = b.w;
    }
}

// one block per feature d; coalesced reads of pS[d*NB..], LDS tree reduce.
__global__ __launch_bounds__(256) void bn_reduce(const float* __restrict__ pS,
                                                 const float* __restrict__ pQ, int nb,
                                                 const float* __restrict__ gamma,
                                                 const float* __restrict__ beta,
                                                 float* __restrict__ scale,
                                                 float* __restrict__ shift, float n) {
    int d = blockIdx.x;
    int tid = threadIdx.x;
    float s = 0.f, q = 0.f;
    for (int b = tid; b < nb; b += 256) {
        s += pS[d * nb + b];
        q += pQ[d * nb + b];
    }
    __shared__ float smS[256], smQ[256];
    smS[tid] = s;
    smQ[tid] = q;
    __syncthreads();
    for (int off = 128; off > 0; off >>= 1) {
        if (tid < off) {
            smS[tid] += smS[tid + off];
            smQ[tid] += smQ[tid + off];
        }
        __syncthreads();
    }
    if (tid == 0) {
        float mean = smS[0] / n;
        float var = smQ[0] / n - mean * mean;
        float rstd = rsqrtf(var + EPSV);
        float sc = gamma[d] * rstd;
        scale[d] = sc;
        shift[d] = beta[d] - mean * sc;
    }
}

// ---------------- GEMM: h = (src*scale+shift) @ W, output bf16 ----------------
// 64 rows/block, 256 threads = 8 rowgroups x 32 colgroups, 8x4 micro-tile.
// k4-blocked: LDS reads are ds_read_b128 (broadcast within half-wave).

template <bool GATHER>
__global__ __launch_bounds__(256) void gemm_bn(const float* __restrict__ src,
                                               const int* __restrict__ idx,
                                               const float* __restrict__ scale,
                                               const float* __restrict__ shift,
                                               const float* __restrict__ W,
                                               unsigned short* __restrict__ outb, int n) {
    __shared__ float xs[64 * 132];  // 33.8 KB
    int tid = threadIdx.x;
    int r0 = blockIdx.x * 64;
    const float4* scale4 = (const float4*)scale;
    const float4* shift4 = (const float4*)shift;
    for (int it = 0; it < 8; ++it) {
        int flat = it * 256 + tid;  // 0..2047
        int r = flat >> 5;          // 0..63
        int kq = flat & 31;         // float4 index along k
        int gr = r0 + r;
        float4 v = make_float4(0.f, 0.f, 0.f, 0.f);
        if (gr < n) {
            int srow = GATHER ? idx[gr] : gr;
            float4 x4 = *(const float4*)&src[(long)srow * D + kq * 4];
            float4 sc = scale4[kq], sh = shift4[kq];
            v = make_float4(x4.x * sc.x + sh.x, x4.y * sc.y + sh.y, x4.z * sc.z + sh.z,
                            x4.w * sc.w + sh.w);
        }
        *(float4*)&xs[r * 132 + kq * 4] = v;
    }
    __syncthreads();
    int cg = tid & 31;  // cols cg*4..cg*4+3
    int rg = tid >> 5;  // rows rg*8..rg*8+7
    float acc[8][4];
#pragma unroll
    for (int j = 0; j < 8; ++j)
#pragma unroll
        for (int q = 0; q < 4; ++q) acc[j][q] = 0.f;
    const float4* Wv = (const float4*)W;
#pragma unroll 2
    for (int k4 = 0; k4 < 128; k4 += 4) {
        float4 wv0 = Wv[(k4 + 0) * 32 + cg];
        float4 wv1 = Wv[(k4 + 1) * 32 + cg];
        float4 wv2 = Wv[(k4 + 2) * 32 + cg];
        float4 wv3 = Wv[(k4 + 3) * 32 + cg];
#pragma unroll
        for (int j = 0; j < 8; ++j) {
            float4 xv = *(const float4*)&xs[(rg * 8 + j) * 132 + k4];
            acc[j][0] += xv.x * wv0.x; acc[j][1] += xv.x * wv0.y;
            acc[j][2] += xv.x * wv0.z; acc[j][3] += xv.x * wv0.w;
            acc[j][0] += xv.y * wv1.x; acc[j][1] += xv.y * wv1.y;
            acc[j][2] += xv.y * wv1.z; acc[j][3] += xv.y * wv1.w;
            acc[j][0] += xv.z * wv2.x; acc[j][1] += xv.z * wv2.y;
            acc[j][2] += xv.z * wv2.z; acc[j][3] += xv.z * wv2.w;
            acc[j][0] += xv.w * wv3.x; acc[j][1] += xv.w * wv3.y;
            acc[j][2] += xv.w * wv3.z; acc[j][3] += xv.w * wv3.w;
        }
    }
#pragma unroll
    for (int j = 0; j < 8; ++j) {
        int gr = r0 + rg * 8 + j;
        if (gr < n) {
            ushort4 o = make_ushort4(f2bf(acc[j][0]), f2bf(acc[j][1]), f2bf(acc[j][2]),
                                     f2bf(acc[j][3]));
            *(ushort4*)&outb[(long)gr * D + cg * 4] = o;
        }
    }
}

// ---------------- aggregation: x[i] = relu(b + sum_e w_e * h[row_e]) ----------------
// h is bf16 (256B rows): 1 node per wave, lane d holds features 2d,2d+1;
// fp32 accumulate; 8-edge unroll.

__global__ __launch_bounds__(256) void agg_kernel(const unsigned int* __restrict__ hw,
                                                  const int2* __restrict__ csr,
                                                  const int* __restrict__ offs,
                                                  const float2* __restrict__ bias2,
                                                  float2* __restrict__ xout, int n) {
    int node = blockIdx.x * 4 + (threadIdx.x >> 6);
    int d = threadIdx.x & 63;
    if (node >= n) return;
    int p0 = offs[node], p1 = offs[node + 1];
    float2 acc = bias2[d];
    int p = p0;
    for (; p + 8 <= p1; p += 8) {
        int2 e0 = csr[p], e1 = csr[p + 1], e2 = csr[p + 2], e3 = csr[p + 3];
        int2 e4 = csr[p + 4], e5 = csr[p + 5], e6 = csr[p + 6], e7 = csr[p + 7];
        unsigned int u0 = hw[(long)e0.x * 64 + d];
        unsigned int u1 = hw[(long)e1.x * 64 + d];
        unsigned int u2 = hw[(long)e2.x * 64 + d];
        unsigned int u3 = hw[(long)e3.x * 64 + d];
        unsigned int u4 = hw[(long)e4.x * 64 + d];
        unsigned int u5 = hw[(long)e5.x * 64 + d];
        unsigned int u6 = hw[(long)e6.x * 64 + d];
        unsigned int u7 = hw[(long)e7.x * 64 + d];
        float w0 = __int_as_float(e0.y), w1 = __int_as_float(e1.y);
        float w2 = __int_as_float(e2.y), w3 = __int_as_float(e3.y);
        float w4 = __int_as_float(e4.y), w5 = __int_as_float(e5.y);
        float w6 = __int_as_float(e6.y), w7 = __int_as_float(e7.y);
        acc.x += w0 * __uint_as_float(u0 << 16); acc.y += w0 * __uint_as_float(u0 & 0xffff0000u);
        acc.x += w1 * __uint_as_float(u1 << 16); acc.y += w1 * __uint_as_float(u1 & 0xffff0000u);
        acc.x += w2 * __uint_as_float(u2 << 16); acc.y += w2 * __uint_as_float(u2 & 0xffff0000u);
        acc.x += w3 * __uint_as_float(u3 << 16); acc.y += w3 * __uint_as_float(u3 & 0xffff0000u);
        acc.x += w4 * __uint_as_float(u4 << 16); acc.y += w4 * __uint_as_float(u4 & 0xffff0000u);
        acc.x += w5 * __uint_as_float(u5 << 16); acc.y += w5 * __uint_as_float(u5 & 0xffff0000u);
        acc.x += w6 * __uint_as_float(u6 << 16); acc.y += w6 * __uint_as_float(u6 & 0xffff0000u);
        acc.x += w7 * __uint_as_float(u7 << 16); acc.y += w7 * __uint_as_float(u7 & 0xffff0000u);
    }
    for (; p < p1; ++p) {
        int2 e = csr[p];
        unsigned int u = hw[(long)e.x * 64 + d];
        float w = __int_as_float(e.y);
        acc.x += w * __uint_as_float(u << 16);
        acc.y += w * __uint_as_float(u & 0xffff0000u);
    }
    xout[(long)node * 64 + d] = make_float2(fmaxf(acc.x, 0.f), fmaxf(acc.y, 0.f));
}

// ---------------- softmax pooling (segment bounds found in-block) ----------------

__global__ __launch_bounds__(512) void pool_kernel(const float* __restrict__ tfidf,
                                                   const int* __restrict__ batch,
                                                   const float* __restrict__ x,
                                                   float* __restrict__ out, int n) {
    int g = blockIdx.x;
    int tid = threadIdx.x;
    __shared__ int sbounds[2];
    if (tid < 2) {
        int target = g + tid;
        int lo = 0, hi = n;
        while (lo < hi) {
            int mid = (lo + hi) >> 1;
            if (batch[mid] < target) lo = mid + 1;
            else hi = mid;
        }
        sbounds[tid] = lo;
    }
    __syncthreads();
    int s0 = sbounds[0], s1 = sbounds[1];
    int d = tid & 127, sub = tid >> 7;  // 4-way node split
    __shared__ float red[512];
    float m = -1e30f;
    for (int i = s0 + tid; i < s1; i += 512) m = fmaxf(m, tfidf[i]);
    red[tid] = m;
    __syncthreads();
    for (int off = 256; off > 0; off >>= 1) {
        if (tid < off) red[tid] = fmaxf(red[tid], red[tid + off]);
        __syncthreads();
    }
    m = red[0];
    __syncthreads();
    float s = 0.f;
    for (int i = s0 + tid; i < s1; i += 512) s += __expf(tfidf[i] - m);
    red[tid] = s;
    __syncthreads();
    for (int off = 256; off > 0; off >>= 1) {
        if (tid < off) red[tid] += red[tid + off];
        __syncthreads();
    }
    s = red[0];
    __syncthreads();
    float acc = 0.f;
    for (int i = s0 + sub; i < s1; i += 4) acc += __expf(tfidf[i] - m) * x[(long)i * D + d];
    red[tid] = acc;
    __syncthreads();
    if (tid < 128) {
        float a = red[d] + red[128 + d] + red[256 + d] + red[384 + d];
        out[g * D + d] = (s1 > s0) ? a / s : 0.f;
    }
}

// ---------------- launch ----------------

extern "C" void kernel_launch(void* const* d_in, const int* in_sizes, int n_in, void* d_out,
                              int out_size, void* d_ws, size_t ws_size, hipStream_t stream) {
    const int N = in_sizes[0];
    const int E = in_sizes[4];
    const int G = out_size / D;
    const int BN_GRID = 768;

    const int* x_index = (const int*)d_in[0];
    const float* tfidf = (const float*)d_in[1];
    const int* ei_row = (const int*)d_in[2];
    const int* ei_col = ei_row + E;
    const int* batch = (const int*)d_in[3];
    const float* edge_attr = (const float*)d_in[4];
    const float* emb = (const float*)d_in[5];
    const float* gamma1 = (const float*)d_in[6];
    const float* beta1 = (const float*)d_in[7];
    const float* W1 = (const float*)d_in[8];
    const float* b1 = (const float*)d_in[9];
    const float* gamma2 = (const float*)d_in[10];
    const float* beta2 = (const float*)d_in[11];
    const float* W2 = (const float*)d_in[12];
    const float* b2 = (const float*)d_in[13];
    float* out = (float*)d_out;

    // ---- workspace carve (256B aligned) ----
    size_t off = 0;
    char* base = (char*)d_ws;
    auto carve = [&](size_t bytes) -> void* {
        void* p = base + off;
        off = (off + bytes + 255) & ~(size_t)255;
        return p;
    };
    unsigned short* bufA = (unsigned short*)carve((size_t)N * D * 2);  // h (bf16)
    float* bufB = (float*)carve((size_t)N * D * 4);                    // x (layer output)
    long long* pk = (long long*)carve((size_t)E * 8);                  // packed (e, row)
    int2* csr = (int2*)carve((size_t)E * 8);                           // (row, ea) -> (row, w)
    int* cnt = (int*)carve((size_t)N * 4);                             // zeroed each launch
    float* dis = (float*)carve((size_t)N * 4);
    int* offs = (int*)carve((size_t)(N + 1) * 4);
    int* cursor = (int*)carve((size_t)N * 4);
    int* bsum = (int*)carve(64 * 4);
    float* scale1 = (float*)carve(D * 4);
    float* shift1 = (float*)carve(D * 4);
    float* scale2 = (float*)carve(D * 4);
    float* shift2 = (float*)carve(D * 4);
    float* pS = (float*)carve((size_t)BN_GRID * D * 4);
    float* pQ = (float*)carve((size_t)BN_GRID * D * 4);
    (void)ws_size;
    (void)n_in;

    hipMemsetAsync(cnt, 0, (size_t)N * 4, stream);

    // ---- edge preprocessing: CSR (deterministic; shared by both layers) ----
    hist_kernel<<<cdiv(E, 256), 256, 0, stream>>>(ei_col, cnt, E);
    int nb = cdiv(N, 1024);
    scan_chunk_sums<<<nb, 1024, 0, stream>>>(cnt, bsum, N);
    scan_final<<<nb, 1024, 0, stream>>>(cnt, bsum, nb, offs, cursor, N, E);
    scatter_pack<<<cdiv(E, 256), 256, 0, stream>>>(ei_row, ei_col, cursor, pk, E);
    sort_deg_kernel<<<cdiv(N, 4), 256, 0, stream>>>(pk, offs, edge_attr, dis, csr, N);
    fill_w_kernel<<<cdiv(N, 4), 256, 0, stream>>>(offs, dis, csr, N);

    // ---- layer 1 ----
    bn_stats<true><<<BN_GRID, 256, 0, stream>>>(emb, x_index, pS, pQ, N, BN_GRID);
    bn_reduce<<<D, 256, 0, stream>>>(pS, pQ, BN_GRID, gamma1, beta1, scale1, shift1, (float)N);
    gemm_bn<true><<<cdiv(N, 64), 256, 0, stream>>>(emb, x_index, scale1, shift1, W1, bufA, N);
    agg_kernel<<<cdiv(N, 4), 256, 0, stream>>>((const unsigned int*)bufA, csr, offs,
                                               (const float2*)b1, (float2*)bufB, N);

    // ---- layer 2 ----
    bn_stats<false><<<BN_GRID, 256, 0, stream>>>(bufB, nullptr, pS, pQ, N, BN_GRID);
    bn_reduce<<<D, 256, 0, stream>>>(pS, pQ, BN_GRID, gamma2, beta2, scale2, shift2, (float)N);
    gemm_bn<false><<<cdiv(N, 64), 256, 0, stream>>>(bufB, nullptr, scale2, shift2, W2, bufA, N);
    agg_kernel<<<cdiv(N, 4), 256, 0, stream>>>((const unsigned int*)bufA, csr, offs,
                                               (const float2*)b2, (float2*)bufB, N);

    // ---- softmax pooling (bounds fused into pool) ----
    pool_kernel<<<G, 512, 0, stream>>>(tfidf, batch, bufB, out, N);
}